// Round 4
// baseline (16.342 us; speedup 1.0000x reference)
//
#include <hip/hip_runtime.h>

// StateStack forward on MI355X.
//
// Reference semantics:
//   new_stack = hidden_stack.at[pos+1, b].set(x)
//   out[k,b,:] = new_stack[pos[b]-1+k, b, :]   k in {0,1}
// pos+1 never collides with {pos-1, pos} at the same column b, so the scatter
// is invisible to the gather -> output reads hidden_stack directly; x/op dead.
//
// Pure memory-bound gather: 32 MB read (2KB contiguous aligned chunks) +
// 32 MB linear write. Roofline ~9.7 us @ 6.6 TB/s (fill-kernel reference).
// R1 (ILP=4) neutral -> latency already hidden by TLP.
// R2/R3: non-temporal load/store (native ext_vector_type for the builtin).

#define SEQ_LEN 64
#define BATCH   8192
#define HIDDEN  512
#define H4      (HIDDEN / 4)   // 128 float4 per row

typedef float f32x4 __attribute__((ext_vector_type(4)));

__global__ __launch_bounds__(256) void StateStack_gather_kernel(
    const f32x4* __restrict__ stack,    // (SEQ_LEN+2, BATCH, H4) as f32x4
    const int*   __restrict__ pos,      // (BATCH,)
    f32x4*       __restrict__ out)      // (2, BATCH, H4) as f32x4
{
    int tid = blockIdx.x * blockDim.x + threadIdx.x;   // 0 .. 2*BATCH*H4
    int h4 = tid & (H4 - 1);
    int bk = tid >> 7;                 // = b + k*BATCH
    int b  = bk & (BATCH - 1);
    int k  = bk >> 13;                 // 0 or 1
    int row = pos[b] - 1 + k;          // in [0, 64]
    size_t src = ((size_t)row * BATCH + (size_t)b) * H4 + h4;
    f32x4 v = __builtin_nontemporal_load(&stack[src]);
    __builtin_nontemporal_store(v, &out[tid]);
}

extern "C" void kernel_launch(void* const* d_in, const int* in_sizes, int n_in,
                              void* d_out, int out_size, void* d_ws, size_t ws_size,
                              hipStream_t stream) {
    // inputs (setup_inputs dict order): x, hidden_stack, op, pos
    const f32x4* stack = (const f32x4*)d_in[1];
    const int*   pos   = (const int*)d_in[3];
    f32x4*       out   = (f32x4*)d_out;

    const int total4 = 2 * BATCH * H4;          // 2,097,152 f32x4
    const int block  = 256;
    const int grid   = total4 / block;          // 8192 blocks
    StateStack_gather_kernel<<<grid, block, 0, stream>>>(stack, pos, out);
}